// Round 5
// baseline (261.552 us; speedup 1.0000x reference)
//
#include <hip/hip_runtime.h>

// Problem dims (fixed by setup_inputs): T=1024, B=8, d=64, n=64
#define T_DIM 1024
#define B_DIM 8
#define D_DIM 64
#define N_DIM 64

typedef float v4f __attribute__((ext_vector_type(4)));

// Decay scan chunking: 64 chunks of 16 timesteps
#define DC_CHUNKS 64
#define DC_LEN 16

// Workspace layout (floats):
//   w    : [T][B][N]   at 0        (524288 floats, 2 MB)
//   lsum : [B][64][N]  at 524288   (32768 floats, 128 KB)
#define WS_W 0
#define WS_LSUM (T_DIM * B_DIM * N_DIM)

// ---------------------------------------------------------------------------
// D1: per-(b, t-chunk) sums of log(max(alpha,1e-8)). lane = n, coalesced rows.
// ---------------------------------------------------------------------------
__global__ __launch_bounds__(64) void decay_chunksum_kernel(
    const float* __restrict__ alpha, float* __restrict__ lsum) {
  const int b = blockIdx.x >> 6;
  const int c = blockIdx.x & 63;
  const int n = threadIdx.x;

  float s = 0.f;
#pragma unroll
  for (int i = 0; i < DC_LEN; ++i) {
    const int t = c * DC_LEN + i;
    s += logf(fmaxf(alpha[((size_t)t * B_DIM + b) * N_DIM + n], 1e-8f));
  }
  lsum[((size_t)b * DC_CHUNKS + c) * N_DIM + n] = s;
}

// ---------------------------------------------------------------------------
// D2: per-(b, t-chunk): gather chunk prefix + total from lsum, emit
//     w[t,b,n] = k * expf(prefix) / (expf(total)+1e-8)
// ---------------------------------------------------------------------------
__global__ __launch_bounds__(64) void decay_w_kernel(
    const float* __restrict__ alpha, const float* __restrict__ kk,
    const float* __restrict__ lsum, float* __restrict__ w) {
  const int b = blockIdx.x >> 6;
  const int c = blockIdx.x & 63;
  const int n = threadIdx.x;

  const float* __restrict__ lp = lsum + (size_t)b * DC_CHUNKS * N_DIM + n;
  float pre = 0.f, tot = 0.f;
#pragma unroll 8
  for (int j = 0; j < DC_CHUNKS; ++j) {
    const float sj = lp[(size_t)j * N_DIM];
    pre += (j < c) ? sj : 0.f;
    tot += sj;
  }
  // Matches reference f32 numerics: expf(tot) underflows -> denom = 1e-8
  const float invden = 1.0f / (expf(tot) + 1e-8f);

  float cum = pre;
#pragma unroll
  for (int i = 0; i < DC_LEN; ++i) {
    const int t = c * DC_LEN + i;
    const size_t idx = ((size_t)t * B_DIM + b) * N_DIM + n;
    cum += logf(fmaxf(alpha[idx], 1e-8f));
    w[idx] = kk[idx] * expf(cum) * invden;
  }
}

// ---------------------------------------------------------------------------
// S (fused): block (c,b,dt). Phase 1: redundantly re-accumulate the chunk
// prefix acc = sum_{t < c*LEN} v[t,b,d]*w[t,b,n] (all L2-resident reads,
// no psum scratch, no extra kernels). Phase 2: emit LEN output steps.
// C=32 -> 1024 blocks x 256 thr = 16 waves/CU.
// ---------------------------------------------------------------------------
template <int C>
__global__ __launch_bounds__(256) void scan_fused_kernel(
    const float* __restrict__ v, const float* __restrict__ ws,
    float* __restrict__ out) {
  constexpr int LEN = T_DIM / C;
  const int bid = blockIdx.x;
  const int dt = bid & 3;
  const int b  = (bid >> 2) & 7;
  const int c  = bid >> 5;
  const int tid = threadIdx.x;
  const int d  = dt * 16 + (tid >> 4);
  const int n0 = (tid & 15) * 4;

  const float* __restrict__ vp = v + (size_t)b * D_DIM + d;
  const float* __restrict__ wp = ws + WS_W + (size_t)b * N_DIM + n0;

  v4f acc = {0.f, 0.f, 0.f, 0.f};

  // Phase 1: redundant prefix recompute over chunks j < c (t-ascending order,
  // same summation order as the reference cumsum).
  for (int j = 0; j < c; ++j) {
#pragma unroll 8
    for (int i = 0; i < LEN; ++i) {
      const int t = j * LEN + i;
      const float vv = vp[(size_t)t * (B_DIM * D_DIM)];
      const v4f w4 = *(const v4f*)(wp + (size_t)t * (B_DIM * N_DIM));
      acc.x = fmaf(vv, w4.x, acc.x);
      acc.y = fmaf(vv, w4.y, acc.y);
      acc.z = fmaf(vv, w4.z, acc.z);
      acc.w = fmaf(vv, w4.w, acc.w);
    }
  }

  // Phase 2: emit this chunk. Per wave: 1KB contiguous float4 stores.
#pragma unroll 8
  for (int i = 0; i < LEN; ++i) {
    const int t = c * LEN + i;
    const float vv = vp[(size_t)t * (B_DIM * D_DIM)];
    const v4f w4 = *(const v4f*)(wp + (size_t)t * (B_DIM * N_DIM));
    acc.x = fmaf(vv, w4.x, acc.x);
    acc.y = fmaf(vv, w4.y, acc.y);
    acc.z = fmaf(vv, w4.z, acc.z);
    acc.w = fmaf(vv, w4.w, acc.w);
    *(v4f*)(out + (((size_t)t * B_DIM + b) * D_DIM + d) * N_DIM + n0) = acc;
  }
}

// ---------------------------------------------------------------------------
extern "C" void kernel_launch(void* const* d_in, const int* in_sizes, int n_in,
                              void* d_out, int out_size, void* d_ws, size_t ws_size,
                              hipStream_t stream) {
  const float* v     = (const float*)d_in[0];
  const float* k     = (const float*)d_in[1];
  const float* alpha = (const float*)d_in[2];
  float* out = (float*)d_out;
  float* ws  = (float*)d_ws;  // needs (524288 + 32768)*4 = 2.23 MB

  float* lsum = ws + WS_LSUM;
  decay_chunksum_kernel<<<B_DIM * DC_CHUNKS, 64, 0, stream>>>(alpha, lsum);
  decay_w_kernel<<<B_DIM * DC_CHUNKS, 64, 0, stream>>>(alpha, k, lsum, ws + WS_W);
  scan_fused_kernel<32><<<32 * B_DIM * 4, 256, 0, stream>>>(v, ws, out);
}

// Round 6
// 159.118 us; speedup vs baseline: 1.6438x; 1.6438x over previous
//
#include <hip/hip_runtime.h>

// Problem dims (fixed by setup_inputs): T=1024, B=8, d=64, n=64
#define T_DIM 1024
#define B_DIM 8
#define D_DIM 64
#define N_DIM 64

typedef float v4f __attribute__((ext_vector_type(4)));

// Decay scan chunking: 64 chunks of 16 timesteps
#define DC_CHUNKS 64
#define DC_LEN 16

// Outer cumsum chunking
#define C_CHUNKS 64
#define C_LEN (T_DIM / C_CHUNKS)  // 16

#define SLAB (B_DIM * D_DIM * N_DIM)  // 32768 floats per chunk slab

// Workspace layout (floats):
//   w    : [T][B][N]       at 0                  (524288)
//   psum : [C][B][D][N]    at 524288             (C_CHUNKS*SLAB = 2097152)
//   lsum : [B][64][N]      after psum            (32768)
#define WS_W 0
#define WS_PSUM (T_DIM * B_DIM * N_DIM)
#define WS_LSUM (WS_PSUM + C_CHUNKS * SLAB)

// ---------------------------------------------------------------------------
// D1: per-(b, t-chunk) sums of log(max(alpha,1e-8)). lane = n, coalesced rows.
// ---------------------------------------------------------------------------
__global__ __launch_bounds__(64) void decay_chunksum_kernel(
    const float* __restrict__ alpha, float* __restrict__ lsum) {
  const int b = blockIdx.x >> 6;
  const int c = blockIdx.x & 63;
  const int n = threadIdx.x;

  float s = 0.f;
#pragma unroll
  for (int i = 0; i < DC_LEN; ++i) {
    const int t = c * DC_LEN + i;
    s += logf(fmaxf(alpha[((size_t)t * B_DIM + b) * N_DIM + n], 1e-8f));
  }
  lsum[((size_t)b * DC_CHUNKS + c) * N_DIM + n] = s;
}

// ---------------------------------------------------------------------------
// D2: per-(b, t-chunk): gather chunk prefix + total from lsum, emit
//     w[t,b,n] = k * expf(prefix) / (expf(total)+1e-8)
// ---------------------------------------------------------------------------
__global__ __launch_bounds__(64) void decay_w_kernel(
    const float* __restrict__ alpha, const float* __restrict__ kk,
    const float* __restrict__ lsum, float* __restrict__ w) {
  const int b = blockIdx.x >> 6;
  const int c = blockIdx.x & 63;
  const int n = threadIdx.x;

  const float* __restrict__ lp = lsum + (size_t)b * DC_CHUNKS * N_DIM + n;
  float pre = 0.f, tot = 0.f;
#pragma unroll 8
  for (int j = 0; j < DC_CHUNKS; ++j) {
    const float sj = lp[(size_t)j * N_DIM];
    pre += (j < c) ? sj : 0.f;
    tot += sj;
  }
  // Matches reference f32 numerics: expf(tot) underflows -> denom = 1e-8
  const float invden = 1.0f / (expf(tot) + 1e-8f);

  float cum = pre;
#pragma unroll
  for (int i = 0; i < DC_LEN; ++i) {
    const int t = c * DC_LEN + i;
    const size_t idx = ((size_t)t * B_DIM + b) * N_DIM + n;
    cum += logf(fmaxf(alpha[idx], 1e-8f));
    w[idx] = kk[idx] * expf(cum) * invden;
  }
}

// ---------------------------------------------------------------------------
// S1: per-chunk partial sums psum[c] = sum_{t in chunk} v[t,b,d]*w[t,b,n].
// Grid = C*B*4 x 256. Thread: d = dt*16 + tid>>4, n0 = (tid&15)*4.
// Loads burst first (independent), then reduce.
// ---------------------------------------------------------------------------
__global__ __launch_bounds__(256) void chunk_psum_kernel(
    const float* __restrict__ v, float* __restrict__ ws) {
  const int bid = blockIdx.x;
  const int dt = bid & 3;
  const int b  = (bid >> 2) & 7;
  const int c  = bid >> 5;
  const int tid = threadIdx.x;
  const int d  = dt * 16 + (tid >> 4);
  const int n0 = (tid & 15) * 4;

  const float* __restrict__ vp = v + (size_t)b * D_DIM + d;
  const float* __restrict__ wp = ws + WS_W + (size_t)b * N_DIM + n0;

  v4f acc = {0.f, 0.f, 0.f, 0.f};
#pragma unroll
  for (int bb = 0; bb < C_LEN / 8; ++bb) {
    float vv[8];
    v4f w4[8];
#pragma unroll
    for (int i = 0; i < 8; ++i) {
      const int t = c * C_LEN + bb * 8 + i;
      vv[i] = vp[(size_t)t * (B_DIM * D_DIM)];
      w4[i] = *(const v4f*)(wp + (size_t)t * (B_DIM * N_DIM));
    }
#pragma unroll
    for (int i = 0; i < 8; ++i) {
      acc.x = fmaf(vv[i], w4[i].x, acc.x);
      acc.y = fmaf(vv[i], w4[i].y, acc.y);
      acc.z = fmaf(vv[i], w4[i].z, acc.z);
      acc.w = fmaf(vv[i], w4[i].w, acc.w);
    }
  }
  *(v4f*)(ws + WS_PSUM + (((size_t)c * B_DIM + b) * D_DIM + d) * N_DIM + n0) = acc;
}

// ---------------------------------------------------------------------------
// S2: acc = sum_{j<c} psum[j] (independent 16B gathers, L2-hit), then two
// 8-step batches: burst-load 8x{v,w4}, serial prefix + store burst.
// Grid = C*B*4 = 2048 blocks x 256 thr.
// ---------------------------------------------------------------------------
__global__ __launch_bounds__(256) void scan_store_kernel(
    const float* __restrict__ v, const float* __restrict__ ws,
    float* __restrict__ out) {
  const int bid = blockIdx.x;
  const int dt = bid & 3;
  const int b  = (bid >> 2) & 7;
  const int c  = bid >> 5;
  const int tid = threadIdx.x;
  const int d  = dt * 16 + (tid >> 4);
  const int n0 = (tid & 15) * 4;

  const float* __restrict__ vp = v + (size_t)b * D_DIM + d;
  const float* __restrict__ wp = ws + WS_W + (size_t)b * N_DIM + n0;
  const float* __restrict__ pp = ws + WS_PSUM + ((size_t)b * D_DIM + d) * N_DIM + n0;

  v4f acc = {0.f, 0.f, 0.f, 0.f};
#pragma unroll 8
  for (int j = 0; j < c; ++j) {
    const v4f p = *(const v4f*)(pp + (size_t)j * SLAB);
    acc.x += p.x; acc.y += p.y; acc.z += p.z; acc.w += p.w;
  }

#pragma unroll
  for (int bb = 0; bb < C_LEN / 8; ++bb) {
    float vv[8];
    v4f w4[8];
#pragma unroll
    for (int i = 0; i < 8; ++i) {
      const int t = c * C_LEN + bb * 8 + i;
      vv[i] = vp[(size_t)t * (B_DIM * D_DIM)];
      w4[i] = *(const v4f*)(wp + (size_t)t * (B_DIM * N_DIM));
    }
#pragma unroll
    for (int i = 0; i < 8; ++i) {
      const int t = c * C_LEN + bb * 8 + i;
      acc.x = fmaf(vv[i], w4[i].x, acc.x);
      acc.y = fmaf(vv[i], w4[i].y, acc.y);
      acc.z = fmaf(vv[i], w4[i].z, acc.z);
      acc.w = fmaf(vv[i], w4[i].w, acc.w);
      *(v4f*)(out + (((size_t)t * B_DIM + b) * D_DIM + d) * N_DIM + n0) = acc;
    }
  }
}

// ---------------------------------------------------------------------------
extern "C" void kernel_launch(void* const* d_in, const int* in_sizes, int n_in,
                              void* d_out, int out_size, void* d_ws, size_t ws_size,
                              hipStream_t stream) {
  const float* v     = (const float*)d_in[0];
  const float* k     = (const float*)d_in[1];
  const float* alpha = (const float*)d_in[2];
  float* out = (float*)d_out;
  float* ws  = (float*)d_ws;  // needs (WS_LSUM + 32768)*4 ~= 10.6 MB

  float* lsum = ws + WS_LSUM;
  decay_chunksum_kernel<<<B_DIM * DC_CHUNKS, 64, 0, stream>>>(alpha, lsum);
  decay_w_kernel<<<B_DIM * DC_CHUNKS, 64, 0, stream>>>(alpha, k, lsum, ws + WS_W);
  chunk_psum_kernel<<<C_CHUNKS * B_DIM * 4, 256, 0, stream>>>(v, ws);
  scan_store_kernel<<<C_CHUNKS * B_DIM * 4, 256, 0, stream>>>(v, ws, out);
}